// Round 1
// baseline (2482.597 us; speedup 1.0000x reference)
//
#include <hip/hip_runtime.h>
#include <hip/hip_fp16.h>
#include <hip/hip_cooperative_groups.h>

namespace cg = cooperative_groups;

typedef _Float16 f16;
typedef _Float16 f16x8 __attribute__((ext_vector_type(8)));
typedef float f32x4 __attribute__((ext_vector_type(4)));

#define S_LEN 128
#define B_SZ  128
#define VOC   10000
#define VPAD  10240
#define HIDN  512

__device__ __forceinline__ void gload_lds16(const void* g, void* l) {
  __builtin_amdgcn_global_load_lds(
      (const __attribute__((address_space(1))) void*)g,
      (__attribute__((address_space(3))) void*)l, 16, 0, 0);
}

// ---- fp32 -> f16 convert, 512 cols, with zero row padding ----
__global__ void convert_pad(const float* __restrict__ src, f16* __restrict__ dst,
                            int rows, int src_stride, int total) {
  int idx = blockIdx.x * 256 + threadIdx.x;
  if (idx >= total) return;
  int r = idx >> 9, c = idx & 511;
  float v = (r < rows) ? src[(size_t)r * src_stride + c] : 0.f;
  dst[idx] = (f16)v;
}

// ---- GEMM: C[M][ldc] = A[*][512] . B[*][512]^T + bias[col]; 128x128 tiles, K=512 ----
// A,B f16 row-major with row stride 512. B indexed [n][k]. CT = f16 or float.
template <typename CT>
__global__ __launch_bounds__(256) void gemm_k512(
    const f16* __restrict__ A, const f16* __restrict__ B,
    CT* __restrict__ C, const float* __restrict__ bias,
    int M, int N, int ldc)
{
  __shared__ f16 Asw[128 * 32];
  __shared__ f16 Bsw[128 * 32];
  const int tid  = threadIdx.x;
  const int lane = tid & 63, w = tid >> 6;
  const int wrow = w >> 1, wcol = w & 1;
  const int m0 = blockIdx.y * 128, n0 = blockIdx.x * 128;
  const int rsel = lane & 15, ksl = lane >> 4;

  f32x4 acc[4][4] = {};

  for (int kt = 0; kt < 16; ++kt) {
    __syncthreads();   // protect LDS from previous iteration's readers
#pragma unroll
    for (int i = 0; i < 2; ++i) {
      int c   = (i * 4 + w) * 64 + lane;
      int row = c >> 2, sp = c & 3;
      int sl  = sp ^ ((row >> 1) & 3);   // source pre-swizzle (rule #21: swizzle src + read, linear dest)
      gload_lds16(A + (size_t)(m0 + row) * 512 + kt * 32 + sl * 8,
                  &Asw[(i * 4 + w) * 512]);
      gload_lds16(B + (size_t)(n0 + row) * 512 + kt * 32 + sl * 8,
                  &Bsw[(i * 4 + w) * 512]);
    }
    __syncthreads();   // drains vmcnt -> staged tile visible
    f16x8 af[4], bf[4];
#pragma unroll
    for (int i = 0; i < 4; ++i) {
      int ar = wrow * 64 + i * 16 + rsel;
      af[i] = *(const f16x8*)&Asw[ar * 32 + ((ksl ^ ((ar >> 1) & 3)) * 8)];
      int br = wcol * 64 + i * 16 + rsel;
      bf[i] = *(const f16x8*)&Bsw[br * 32 + ((ksl ^ ((br >> 1) & 3)) * 8)];
    }
#pragma unroll
    for (int i = 0; i < 4; ++i)
#pragma unroll
      for (int j = 0; j < 4; ++j)
        acc[i][j] = __builtin_amdgcn_mfma_f32_16x16x32_f16(af[i], bf[j], acc[i][j], 0, 0, 0);
  }

#pragma unroll
  for (int tc = 0; tc < 4; ++tc) {
    int col = n0 + wcol * 64 + tc * 16 + rsel;
    if (col >= N) continue;
    float bv = bias ? bias[col] : 0.f;
#pragma unroll
    for (int i = 0; i < 4; ++i) {
      int rowb = m0 + wrow * 64 + i * 16 + ksl * 4;
#pragma unroll
      for (int j = 0; j < 4; ++j) {
        int row = rowb + j;
        if (row < M) C[(size_t)row * ldc + col] = (CT)(acc[i][tc][j] + bv);
      }
    }
  }
}

// ---- cooperative recurrence: 64 blocks = 32 colgroups(16 cols) x 2 batchgroups(64 rows) ----
// phase p: computes h0(p) (p<128) and h1(p-1) (p>0); 129 phases, grid.sync between.
__global__ __launch_bounds__(256) void rnn_recur(
    const int* __restrict__ tok,    // [128][128]
    const float* __restrict__ W0,   // [512][1024]
    const float* __restrict__ W1,   // [512][1024]
    const float* __restrict__ b1,   // [512]
    const f16* __restrict__ P0h,    // [10000][512]  emb@W0x^T + b0
    f16* __restrict__ h0pp,         // [2][128][512] ping-pong ([1] = initial h0)
    const f16* __restrict__ h1init, // [128][512]
    f16* __restrict__ H1,           // [128][128][512]
    float* __restrict__ outHid)     // [2][128][512] (d_out tail)
{
  __shared__ f16 wlds[3][16 * 512];   // W0h^T, W1a^T, W1b^T column slices, XOR-swizzled
  const int tid = threadIdx.x;
  const int lane = tid & 63, w = tid >> 6;
  const int cgI = blockIdx.x & 31, bg = blockIdx.x >> 5;
  const int col0 = cgI * 16;
  const int rowstart = bg * 64 + w * 16;
  const int rsel = lane & 15, ksl = lane >> 4;

  // load resident weight slices (one time): slice s, col c (unit n=col0+c), 16B chunk ks
  for (int it = tid; it < 3 * 16 * 64; it += 256) {
    int s = it >> 10;
    int rem = it & 1023;
    int c = rem >> 6, ks = rem & 63;
    int n = col0 + c;
    const float* srcp;
    if (s == 0)      srcp = W0 + (size_t)n * 1024 + 512 + ks * 8;  // W0h
    else if (s == 1) srcp = W1 + (size_t)n * 1024 + ks * 8;        // W1a
    else             srcp = W1 + (size_t)n * 1024 + 512 + ks * 8;  // W1b
    f16x8 v;
#pragma unroll
    for (int j = 0; j < 8; ++j) v[j] = (f16)srcp[j];
    *(f16x8*)&wlds[s][c * 512 + ((ks ^ (c & 7)) * 8)] = v;
  }
  float b1v = b1[col0 + rsel];
  __syncthreads();

  cg::grid_group grid = cg::this_grid();
  const int rbase = rowstart + ksl * 4;

  for (int p = 0; p <= S_LEN; ++p) {
    const f16* h0prev = h0pp + (size_t)((p + 1) & 1) * B_SZ * HIDN;  // h0(p-1)
    if (p < S_LEN) {
      f32x4 acc;
#pragma unroll
      for (int j = 0; j < 4; ++j) {
        int t_ = tok[p * B_SZ + rbase + j];
        acc[j] = (float)P0h[(size_t)t_ * HIDN + col0 + rsel];
      }
#pragma unroll
      for (int kt = 0; kt < 16; ++kt) {
        f16x8 a = *(const f16x8*)&h0prev[(size_t)(rowstart + rsel) * HIDN + kt * 32 + ksl * 8];
        int ks = kt * 4 + ksl;
        f16x8 b = *(const f16x8*)&wlds[0][rsel * 512 + ((ks ^ (rsel & 7)) * 8)];
        acc = __builtin_amdgcn_mfma_f32_16x16x32_f16(a, b, acc, 0, 0, 0);
      }
      f16* h0out = h0pp + (size_t)(p & 1) * B_SZ * HIDN;
#pragma unroll
      for (int j = 0; j < 4; ++j) {
        float v = tanhf(acc[j]);
        int r = rbase + j;
        h0out[(size_t)r * HIDN + col0 + rsel] = (f16)v;
        if (p == S_LEN - 1) outHid[(size_t)r * HIDN + col0 + rsel] = v;
      }
    }
    if (p > 0) {
      const f16* h1prev = (p == 1) ? h1init : H1 + (size_t)(p - 2) * B_SZ * HIDN;
      f32x4 acc;
#pragma unroll
      for (int j = 0; j < 4; ++j) acc[j] = b1v;
#pragma unroll
      for (int kt = 0; kt < 16; ++kt) {
        f16x8 a = *(const f16x8*)&h0prev[(size_t)(rowstart + rsel) * HIDN + kt * 32 + ksl * 8];
        int ks = kt * 4 + ksl;
        f16x8 b = *(const f16x8*)&wlds[1][rsel * 512 + ((ks ^ (rsel & 7)) * 8)];
        acc = __builtin_amdgcn_mfma_f32_16x16x32_f16(a, b, acc, 0, 0, 0);
      }
#pragma unroll
      for (int kt = 0; kt < 16; ++kt) {
        f16x8 a = *(const f16x8*)&h1prev[(size_t)(rowstart + rsel) * HIDN + kt * 32 + ksl * 8];
        int ks = kt * 4 + ksl;
        f16x8 b = *(const f16x8*)&wlds[2][rsel * 512 + ((ks ^ (rsel & 7)) * 8)];
        acc = __builtin_amdgcn_mfma_f32_16x16x32_f16(a, b, acc, 0, 0, 0);
      }
      f16* h1out = H1 + (size_t)(p - 1) * B_SZ * HIDN;
#pragma unroll
      for (int j = 0; j < 4; ++j) {
        float v = tanhf(acc[j]);
        int r = rbase + j;
        h1out[(size_t)r * HIDN + col0 + rsel] = (f16)v;
        if (p == S_LEN) outHid[(size_t)(B_SZ * HIDN) + (size_t)r * HIDN + col0 + rsel] = v;
      }
    }
    if (p < S_LEN) grid.sync();
  }
}

extern "C" void kernel_launch(void* const* d_in, const int* in_sizes, int n_in,
                              void* d_out, int out_size, void* d_ws, size_t ws_size,
                              hipStream_t stream) {
  (void)in_sizes; (void)n_in; (void)out_size; (void)ws_size;
  const int*   tok    = (const int*)d_in[0];
  const float* hidden = (const float*)d_in[1];
  const float* emb    = (const float*)d_in[2];
  const float* W0     = (const float*)d_in[3];
  const float* b0     = (const float*)d_in[4];
  const float* W1     = (const float*)d_in[5];
  const float* b1     = (const float*)d_in[6];
  const float* Wout   = (const float*)d_in[7];
  const float* bout   = (const float*)d_in[8];

  char* ws = (char*)d_ws;
  size_t off = 0;
  f16* embf16  = (f16*)(ws + off); off += (size_t)VPAD * 512 * 2;   // zero-padded emb
  f16* woutf16 = (f16*)(ws + off); off += (size_t)VPAD * 512 * 2;   // zero-padded Wout
  f16* w0xf16  = (f16*)(ws + off); off += (size_t)512 * 512 * 2;    // W0[:, :512] packed
  f16* P0h     = (f16*)(ws + off); off += (size_t)VOC * 512 * 2;    // emb@W0x^T + b0
  f16* H1      = (f16*)(ws + off); off += (size_t)S_LEN * B_SZ * 512 * 2;
  f16* h0pp    = (f16*)(ws + off); off += (size_t)2 * B_SZ * 512 * 2;
  f16* h1init  = (f16*)(ws + off); off += (size_t)B_SZ * 512 * 2;

  float* outHid = (float*)d_out + (size_t)S_LEN * B_SZ * VOC;

  int tot = VPAD * 512;
  convert_pad<<<(tot + 255) / 256, 256, 0, stream>>>(emb,  embf16,  VOC, 512, tot);
  convert_pad<<<(tot + 255) / 256, 256, 0, stream>>>(Wout, woutf16, VOC, 512, tot);
  tot = 512 * 512;
  convert_pad<<<(tot + 255) / 256, 256, 0, stream>>>(W0, w0xf16, 512, 1024, tot);
  tot = B_SZ * 512;
  convert_pad<<<(tot + 255) / 256, 256, 0, stream>>>(hidden, h0pp + (size_t)B_SZ * 512, B_SZ, 512, tot);
  convert_pad<<<(tot + 255) / 256, 256, 0, stream>>>(hidden + (size_t)B_SZ * 512, h1init, B_SZ, 512, tot);

  // P0 = emb @ W0x^T + b0  (f16 out, [10000][512])
  gemm_k512<f16><<<dim3(4, VPAD / 128), 256, 0, stream>>>(
      embf16, w0xf16, P0h, b0, VOC, 512, 512);

  // recurrence (cooperative, 129 phases)
  {
    void* args[] = {(void*)&tok, (void*)&W0, (void*)&W1, (void*)&b1, (void*)&P0h,
                    (void*)&h0pp, (void*)&h1init, (void*)&H1, (void*)&outHid};
    hipLaunchCooperativeKernel((const void*)rnn_recur, dim3(64), dim3(256), args, 0, stream);
  }

  // logits = H1 @ Wout^T + bout  -> d_out [16384][10000] fp32
  gemm_k512<float><<<dim3(79, 128), 256, 0, stream>>>(
      H1, woutf16, (float*)d_out, bout, S_LEN * B_SZ, VOC, VOC);
}

// Round 2
// 2068.722 us; speedup vs baseline: 1.2001x; 1.2001x over previous
//
#include <hip/hip_runtime.h>
#include <hip/hip_fp16.h>

typedef _Float16 f16;
typedef _Float16 f16x4 __attribute__((ext_vector_type(4)));
typedef _Float16 f16x8 __attribute__((ext_vector_type(8)));
typedef float f32x4 __attribute__((ext_vector_type(4)));

#define S_LEN 128
#define B_SZ  128
#define VOC   10000
#define VPAD  10240
#define HIDN  512
#define NBLK  64

__device__ __forceinline__ void gload_lds16(const void* g, void* l) {
  __builtin_amdgcn_global_load_lds(
      (const __attribute__((address_space(1))) void*)g,
      (__attribute__((address_space(3))) void*)l, 16, 0, 0);
}

// coherent (agent-scope, L2-bypassing) 16B load as two 8B atomic loads
union HU { unsigned long long u; f16x4 h; };
__device__ __forceinline__ f16x8 cload16(const f16* p) {
  HU a, b;
  a.u = __hip_atomic_load((const unsigned long long*)p,     __ATOMIC_RELAXED, __HIP_MEMORY_SCOPE_AGENT);
  b.u = __hip_atomic_load((const unsigned long long*)p + 1, __ATOMIC_RELAXED, __HIP_MEMORY_SCOPE_AGENT);
  return __builtin_shufflevector(a.h, b.h, 0, 1, 2, 3, 4, 5, 6, 7);
}
// coherent (write-through) 2B store
__device__ __forceinline__ void cstore2(f16* p, float v) {
  f16 h = (f16)v;
  unsigned short u = __builtin_bit_cast(unsigned short, h);
  __hip_atomic_store((unsigned short*)p, u, __ATOMIC_RELAXED, __HIP_MEMORY_SCOPE_AGENT);
}

// ---- fp32 -> f16 convert, 512 cols, with zero row padding ----
__global__ void convert_pad(const float* __restrict__ src, f16* __restrict__ dst,
                            int rows, int src_stride, int total) {
  int idx = blockIdx.x * 256 + threadIdx.x;
  if (idx >= total) return;
  int r = idx >> 9, c = idx & 511;
  float v = (r < rows) ? src[(size_t)r * src_stride + c] : 0.f;
  dst[idx] = (f16)v;
}

// ---- GEMM: C[M][ldc] = A[*][512] . B[*][512]^T + bias[col]; 128x128 tiles, K=512 ----
template <typename CT>
__global__ __launch_bounds__(256) void gemm_k512(
    const f16* __restrict__ A, const f16* __restrict__ B,
    CT* __restrict__ C, const float* __restrict__ bias,
    int M, int N, int ldc)
{
  __shared__ f16 Asw[128 * 32];
  __shared__ f16 Bsw[128 * 32];
  const int tid  = threadIdx.x;
  const int lane = tid & 63, w = tid >> 6;
  const int wrow = w >> 1, wcol = w & 1;
  // XCD-aware bijective swizzle on flattened block id (nwg % 8 == 0 for our grids)
  int nwg  = gridDim.x * gridDim.y;
  int orig = blockIdx.y * gridDim.x + blockIdx.x;
  int cpx  = nwg >> 3;
  int swz  = (orig & 7) * cpx + (orig >> 3);
  const int m0 = (swz / gridDim.x) * 128, n0 = (swz % gridDim.x) * 128;
  const int rsel = lane & 15, ksl = lane >> 4;

  f32x4 acc[4][4] = {};

  for (int kt = 0; kt < 16; ++kt) {
    __syncthreads();   // protect LDS from previous iteration's readers
#pragma unroll
    for (int i = 0; i < 2; ++i) {
      int c   = (i * 4 + w) * 64 + lane;
      int row = c >> 2, sp = c & 3;
      int sl  = sp ^ ((row >> 1) & 3);   // source pre-swizzle (linear LDS dest)
      gload_lds16(A + (size_t)(m0 + row) * 512 + kt * 32 + sl * 8,
                  &Asw[(i * 4 + w) * 512]);
      gload_lds16(B + (size_t)(n0 + row) * 512 + kt * 32 + sl * 8,
                  &Bsw[(i * 4 + w) * 512]);
    }
    __syncthreads();   // drains vmcnt -> staged tile visible
    f16x8 af[4], bf[4];
#pragma unroll
    for (int i = 0; i < 4; ++i) {
      int ar = wrow * 64 + i * 16 + rsel;
      af[i] = *(const f16x8*)&Asw[ar * 32 + ((ksl ^ ((ar >> 1) & 3)) * 8)];
      int br = wcol * 64 + i * 16 + rsel;
      bf[i] = *(const f16x8*)&Bsw[br * 32 + ((ksl ^ ((br >> 1) & 3)) * 8)];
    }
#pragma unroll
    for (int i = 0; i < 4; ++i)
#pragma unroll
      for (int j = 0; j < 4; ++j)
        acc[i][j] = __builtin_amdgcn_mfma_f32_16x16x32_f16(af[i], bf[j], acc[i][j], 0, 0, 0);
  }

#pragma unroll
  for (int tc = 0; tc < 4; ++tc) {
    int col = n0 + wcol * 64 + tc * 16 + rsel;
    if (col >= N) continue;
    float bv = bias ? bias[col] : 0.f;
#pragma unroll
    for (int i = 0; i < 4; ++i) {
      int rowb = m0 + wrow * 64 + i * 16 + ksl * 4;
#pragma unroll
      for (int j = 0; j < 4; ++j) {
        int row = rowb + j;
        if (row < M) C[(size_t)row * ldc + col] = (CT)(acc[i][tc][j] + bv);
      }
    }
  }
}

// ---- cooperative recurrence: 64 blocks = 32 colgroups(16 cols) x 2 batchgroups(64 rows) ----
// phase p: computes h0(p) (p<128) and h1(p-1) (p>0); custom device-scope barrier between
// phases (targeted coherence: agent-atomic h loads/stores; no cache-wide fences).
__global__ __launch_bounds__(256, 1) void rnn_recur(
    const int* __restrict__ tok,    // [128][128]
    const float* __restrict__ W0,   // [512][1024]
    const float* __restrict__ W1,   // [512][1024]
    const float* __restrict__ b1,   // [512]
    const f16* __restrict__ P0h,    // [10000][512]  emb@W0x^T + b0
    f16* __restrict__ h0pp,         // [2][128][512] ping-pong ([1] = initial h0)
    const f16* __restrict__ h1init, // [128][512]
    f16* __restrict__ H1,           // [128][128][512]
    float* __restrict__ outHid,     // [2][128][512] (d_out tail)
    unsigned* __restrict__ cnt)     // barrier counter (reset to 0 each launch)
{
  __shared__ f16 wlds[3][16 * 512];   // W0h^T, W1a^T, W1b^T column slices, XOR-swizzled
  const int tid = threadIdx.x;
  const int lane = tid & 63, w = tid >> 6;
  const int cgI = blockIdx.x & 31, bg = blockIdx.x >> 5;
  const int col0 = cgI * 16;
  const int rowstart = bg * 64 + w * 16;
  const int rsel = lane & 15, ksl = lane >> 4;

  // load resident weight slices (one time)
  for (int it = tid; it < 3 * 16 * 64; it += 256) {
    int s = it >> 10;
    int rem = it & 1023;
    int c = rem >> 6, ks = rem & 63;
    int n = col0 + c;
    const float* srcp;
    if (s == 0)      srcp = W0 + (size_t)n * 1024 + 512 + ks * 8;  // W0h
    else if (s == 1) srcp = W1 + (size_t)n * 1024 + ks * 8;        // W1a
    else             srcp = W1 + (size_t)n * 1024 + 512 + ks * 8;  // W1b
    f16x8 v;
#pragma unroll
    for (int j = 0; j < 8; ++j) v[j] = (f16)srcp[j];
    *(f16x8*)&wlds[s][c * 512 + ((ks ^ (c & 7)) * 8)] = v;
  }
  float b1v = b1[col0 + rsel];
  __syncthreads();

  const int rbase = rowstart + ksl * 4;
  const size_t hrow = (size_t)(rowstart + rsel) * HIDN;

  for (int p = 0; p <= S_LEN; ++p) {
    const f16* h0prev = h0pp + (size_t)((p + 1) & 1) * B_SZ * HIDN;  // h0(p-1)

    // h0prev fragments: shared by the W0h-matmul (p<128) and the W1a-matmul (p>0)
    f16x8 hf[16];
#pragma unroll
    for (int kt = 0; kt < 16; ++kt)
      hf[kt] = cload16(h0prev + hrow + kt * 32 + ksl * 8);

    f16x8 h1f[16];
    if (p > 0) {
      const f16* h1prev = (p == 1) ? h1init : H1 + (size_t)(p - 2) * B_SZ * HIDN;
#pragma unroll
      for (int kt = 0; kt < 16; ++kt)
        h1f[kt] = cload16(h1prev + hrow + kt * 32 + ksl * 8);
    }

    if (p < S_LEN) {
      f32x4 acc;
#pragma unroll
      for (int j = 0; j < 4; ++j) {
        int t_ = tok[p * B_SZ + rbase + j];
        acc[j] = (float)P0h[(size_t)t_ * HIDN + col0 + rsel];   // normal cached load
      }
#pragma unroll
      for (int kt = 0; kt < 16; ++kt) {
        int ks = kt * 4 + ksl;
        f16x8 b = *(const f16x8*)&wlds[0][rsel * 512 + ((ks ^ (rsel & 7)) * 8)];
        acc = __builtin_amdgcn_mfma_f32_16x16x32_f16(hf[kt], b, acc, 0, 0, 0);
      }
      f16* h0out = h0pp + (size_t)(p & 1) * B_SZ * HIDN;
#pragma unroll
      for (int j = 0; j < 4; ++j) {
        float v = tanhf(acc[j]);
        int r = rbase + j;
        cstore2(&h0out[(size_t)r * HIDN + col0 + rsel], v);
        if (p == S_LEN - 1) outHid[(size_t)r * HIDN + col0 + rsel] = v;
      }
    }
    if (p > 0) {
      f32x4 acc;
#pragma unroll
      for (int j = 0; j < 4; ++j) acc[j] = b1v;
#pragma unroll
      for (int kt = 0; kt < 16; ++kt) {
        int ks = kt * 4 + ksl;
        f16x8 b = *(const f16x8*)&wlds[1][rsel * 512 + ((ks ^ (rsel & 7)) * 8)];
        acc = __builtin_amdgcn_mfma_f32_16x16x32_f16(hf[kt], b, acc, 0, 0, 0);
      }
#pragma unroll
      for (int kt = 0; kt < 16; ++kt) {
        int ks = kt * 4 + ksl;
        f16x8 b = *(const f16x8*)&wlds[2][rsel * 512 + ((ks ^ (rsel & 7)) * 8)];
        acc = __builtin_amdgcn_mfma_f32_16x16x32_f16(h1f[kt], b, acc, 0, 0, 0);
      }
      f16* h1out = H1 + (size_t)(p - 1) * B_SZ * HIDN;
#pragma unroll
      for (int j = 0; j < 4; ++j) {
        float v = tanhf(acc[j]);
        int r = rbase + j;
        cstore2(&h1out[(size_t)r * HIDN + col0 + rsel], v);
        if (p == S_LEN) outHid[(size_t)(B_SZ * HIDN) + (size_t)r * HIDN + col0 + rsel] = v;
      }
    }

    if (p < S_LEN) {
      // release: drain this wave's (write-through) stores to the coherence point
      asm volatile("s_waitcnt vmcnt(0)" ::: "memory");
      __syncthreads();
      if (tid == 0) {
        __hip_atomic_fetch_add(cnt, 1u, __ATOMIC_ACQ_REL, __HIP_MEMORY_SCOPE_AGENT);
        unsigned tgt = (unsigned)NBLK * (p + 1);
        while (__hip_atomic_load(cnt, __ATOMIC_ACQUIRE, __HIP_MEMORY_SCOPE_AGENT) < tgt) {}
      }
      __syncthreads();
    }
  }
}

extern "C" void kernel_launch(void* const* d_in, const int* in_sizes, int n_in,
                              void* d_out, int out_size, void* d_ws, size_t ws_size,
                              hipStream_t stream) {
  (void)in_sizes; (void)n_in; (void)out_size; (void)ws_size;
  const int*   tok    = (const int*)d_in[0];
  const float* hidden = (const float*)d_in[1];
  const float* emb    = (const float*)d_in[2];
  const float* W0     = (const float*)d_in[3];
  const float* b0     = (const float*)d_in[4];
  const float* W1     = (const float*)d_in[5];
  const float* b1     = (const float*)d_in[6];
  const float* Wout   = (const float*)d_in[7];
  const float* bout   = (const float*)d_in[8];

  char* ws = (char*)d_ws;
  size_t off = 0;
  f16* embf16  = (f16*)(ws + off); off += (size_t)VPAD * 512 * 2;   // zero-padded emb
  f16* woutf16 = (f16*)(ws + off); off += (size_t)VPAD * 512 * 2;   // zero-padded Wout
  f16* w0xf16  = (f16*)(ws + off); off += (size_t)512 * 512 * 2;    // W0[:, :512] packed
  f16* P0h     = (f16*)(ws + off); off += (size_t)VOC * 512 * 2;    // emb@W0x^T + b0
  f16* H1      = (f16*)(ws + off); off += (size_t)S_LEN * B_SZ * 512 * 2;
  f16* h0pp    = (f16*)(ws + off); off += (size_t)2 * B_SZ * 512 * 2;
  f16* h1init  = (f16*)(ws + off); off += (size_t)B_SZ * 512 * 2;
  unsigned* cnt = (unsigned*)(ws + off); off += 64;                  // barrier counter

  float* outHid = (float*)d_out + (size_t)S_LEN * B_SZ * VOC;

  hipMemsetAsync(cnt, 0, 4, stream);   // reset barrier each launch (capture-safe)

  int tot = VPAD * 512;
  convert_pad<<<(tot + 255) / 256, 256, 0, stream>>>(emb,  embf16,  VOC, 512, tot);
  convert_pad<<<(tot + 255) / 256, 256, 0, stream>>>(Wout, woutf16, VOC, 512, tot);
  tot = 512 * 512;
  convert_pad<<<(tot + 255) / 256, 256, 0, stream>>>(W0, w0xf16, 512, 1024, tot);
  tot = B_SZ * 512;
  convert_pad<<<(tot + 255) / 256, 256, 0, stream>>>(hidden, h0pp + (size_t)B_SZ * 512, B_SZ, 512, tot);
  convert_pad<<<(tot + 255) / 256, 256, 0, stream>>>(hidden + (size_t)B_SZ * 512, h1init, B_SZ, 512, tot);

  // P0 = emb @ W0x^T + b0  (f16 out, [10000][512])
  gemm_k512<f16><<<dim3(4, VPAD / 128), 256, 0, stream>>>(
      embf16, w0xf16, P0h, b0, VOC, 512, 512);

  // recurrence (cooperative for co-residency; custom barrier inside)
  {
    void* args[] = {(void*)&tok, (void*)&W0, (void*)&W1, (void*)&b1, (void*)&P0h,
                    (void*)&h0pp, (void*)&h1init, (void*)&H1, (void*)&outHid, (void*)&cnt};
    hipLaunchCooperativeKernel((const void*)rnn_recur, dim3(NBLK), dim3(256), args, 0, stream);
  }

  // logits = H1 @ Wout^T + bout  -> d_out [16384][10000] fp32
  gemm_k512<float><<<dim3(79, 128), 256, 0, stream>>>(
      H1, woutf16, (float*)d_out, bout, S_LEN * B_SZ, VOC, VOC);
}

// Round 3
// 1700.149 us; speedup vs baseline: 1.4602x; 1.2168x over previous
//
#include <hip/hip_runtime.h>
#include <hip/hip_fp16.h>

typedef _Float16 f16;
typedef _Float16 f16x4 __attribute__((ext_vector_type(4)));
typedef _Float16 f16x8 __attribute__((ext_vector_type(8)));
typedef float f32x4 __attribute__((ext_vector_type(4)));

#define S_LEN 128
#define B_SZ  128
#define VOC   10000
#define VPAD  10240
#define HIDN  512
#define NBLK  64

__device__ __forceinline__ void gload_lds16(const void* g, void* l) {
  __builtin_amdgcn_global_load_lds(
      (const __attribute__((address_space(1))) void*)g,
      (__attribute__((address_space(3))) void*)l, 16, 0, 0);
}

// coherence-point (agent-scope, L2-bypassing) 16B load as two 8B atomic loads
union HU { unsigned long long u; f16x4 h; };
__device__ __forceinline__ f16x8 cload16(const f16* p) {
  HU a, b;
  a.u = __hip_atomic_load((const unsigned long long*)p,     __ATOMIC_RELAXED, __HIP_MEMORY_SCOPE_AGENT);
  b.u = __hip_atomic_load((const unsigned long long*)p + 1, __ATOMIC_RELAXED, __HIP_MEMORY_SCOPE_AGENT);
  return __builtin_shufflevector(a.h, b.h, 0, 1, 2, 3, 4, 5, 6, 7);
}
// write-through 2B store
__device__ __forceinline__ void cstore2(f16* p, float v) {
  f16 h = (f16)v;
  unsigned short u = __builtin_bit_cast(unsigned short, h);
  __hip_atomic_store((unsigned short*)p, u, __ATOMIC_RELAXED, __HIP_MEMORY_SCOPE_AGENT);
}

// tanh via v_exp + v_rcp (~15 cy vs libm's branchy path); clamp keeps exp finite
__device__ __forceinline__ float fast_tanh(float x) {
  float cx = fminf(8.f, fmaxf(-8.f, x));
  float e = __expf(2.f * cx);
  float d = e + 1.f, r;
  asm("v_rcp_f32 %0, %1" : "=v"(r) : "v"(d));
  return (e - 1.f) * r;
}

// ---- fp32 -> f16 convert, 512 cols, with zero row padding ----
__global__ void convert_pad(const float* __restrict__ src, f16* __restrict__ dst,
                            int rows, int src_stride, int total) {
  int idx = blockIdx.x * 256 + threadIdx.x;
  if (idx >= total) return;
  int r = idx >> 9, c = idx & 511;
  float v = (r < rows) ? src[(size_t)r * src_stride + c] : 0.f;
  dst[idx] = (f16)v;
}

// ---- GEMM: C[M][ldc] = A[*][512] . B[*][512]^T + bias[col]; 128x128 tiles, K=512 ----
template <typename CT>
__global__ __launch_bounds__(256) void gemm_k512(
    const f16* __restrict__ A, const f16* __restrict__ B,
    CT* __restrict__ C, const float* __restrict__ bias,
    int M, int N, int ldc)
{
  __shared__ f16 Asw[128 * 32];
  __shared__ f16 Bsw[128 * 32];
  const int tid  = threadIdx.x;
  const int lane = tid & 63, w = tid >> 6;
  const int wrow = w >> 1, wcol = w & 1;
  int nwg  = gridDim.x * gridDim.y;
  int orig = blockIdx.y * gridDim.x + blockIdx.x;
  int cpx  = nwg >> 3;
  int swz  = (orig & 7) * cpx + (orig >> 3);
  const int m0 = (swz / gridDim.x) * 128, n0 = (swz % gridDim.x) * 128;
  const int rsel = lane & 15, ksl = lane >> 4;

  f32x4 acc[4][4] = {};

  for (int kt = 0; kt < 16; ++kt) {
    __syncthreads();
#pragma unroll
    for (int i = 0; i < 2; ++i) {
      int c   = (i * 4 + w) * 64 + lane;
      int row = c >> 2, sp = c & 3;
      int sl  = sp ^ ((row >> 1) & 3);
      gload_lds16(A + (size_t)(m0 + row) * 512 + kt * 32 + sl * 8,
                  &Asw[(i * 4 + w) * 512]);
      gload_lds16(B + (size_t)(n0 + row) * 512 + kt * 32 + sl * 8,
                  &Bsw[(i * 4 + w) * 512]);
    }
    __syncthreads();
    f16x8 af[4], bf[4];
#pragma unroll
    for (int i = 0; i < 4; ++i) {
      int ar = wrow * 64 + i * 16 + rsel;
      af[i] = *(const f16x8*)&Asw[ar * 32 + ((ksl ^ ((ar >> 1) & 3)) * 8)];
      int br = wcol * 64 + i * 16 + rsel;
      bf[i] = *(const f16x8*)&Bsw[br * 32 + ((ksl ^ ((br >> 1) & 3)) * 8)];
    }
#pragma unroll
    for (int i = 0; i < 4; ++i)
#pragma unroll
      for (int j = 0; j < 4; ++j)
        acc[i][j] = __builtin_amdgcn_mfma_f32_16x16x32_f16(af[i], bf[j], acc[i][j], 0, 0, 0);
  }

#pragma unroll
  for (int tc = 0; tc < 4; ++tc) {
    int col = n0 + wcol * 64 + tc * 16 + rsel;
    if (col >= N) continue;
    float bv = bias ? bias[col] : 0.f;
#pragma unroll
    for (int i = 0; i < 4; ++i) {
      int rowb = m0 + wrow * 64 + i * 16 + ksl * 4;
#pragma unroll
      for (int j = 0; j < 4; ++j) {
        int row = rowb + j;
        if (row < M) C[(size_t)row * ldc + col] = (CT)(acc[i][tc][j] + bv);
      }
    }
  }
}

// ---- cooperative recurrence, shadow-pipelined ----
// phase p (0..129):
//   SHADOW (pre-wait):  part1 = b1 + W1a@h0(p-2)   [hf registers from main(p-1)]
//                       P0 token gather for h0(p)
//   WAIT barrier(p-1)
//   MAIN:  load hf=h0(p-1); h0(p)=tanh(P0+W0h@hf)          [p<=127]
//          load h1f=h1(p-3); h1(p-2)=tanh(part1+W1b@h1f)   [p>=2]
//   ARRIVE barrier(p)                                       [p<=128]
__global__ __launch_bounds__(256, 1) void rnn_recur(
    const int* __restrict__ tok,    // [128][128]
    const float* __restrict__ W0,   // [512][1024]
    const float* __restrict__ W1,   // [512][1024]
    const float* __restrict__ b1,   // [512]
    const f16* __restrict__ P0h,    // [10000][512]  emb@W0x^T + b0
    f16* __restrict__ h0ring,       // [4][128][512] (slot 3 = initial h0)
    const f16* __restrict__ h1init, // [128][512]
    f16* __restrict__ H1,           // [128][128][512]
    float* __restrict__ outHid,     // [2][128][512] (d_out tail)
    unsigned* __restrict__ cnt)     // barrier counter (reset to 0 each launch)
{
  __shared__ f16 wlds[3][16 * 512];   // W0h^T, W1a^T, W1b^T column slices, XOR-swizzled
  const int tid = threadIdx.x;
  const int lane = tid & 63, w = tid >> 6;
  const int cgI = blockIdx.x & 31, bg = blockIdx.x >> 5;
  const int col0 = cgI * 16;
  const int rowstart = bg * 64 + w * 16;
  const int rsel = lane & 15, ksl = lane >> 4;

  for (int it = tid; it < 3 * 16 * 64; it += 256) {
    int s = it >> 10;
    int rem = it & 1023;
    int c = rem >> 6, ks = rem & 63;
    int n = col0 + c;
    const float* srcp;
    if (s == 0)      srcp = W0 + (size_t)n * 1024 + 512 + ks * 8;  // W0h
    else if (s == 1) srcp = W1 + (size_t)n * 1024 + ks * 8;        // W1a
    else             srcp = W1 + (size_t)n * 1024 + 512 + ks * 8;  // W1b
    f16x8 v;
#pragma unroll
    for (int j = 0; j < 8; ++j) v[j] = (f16)srcp[j];
    *(f16x8*)&wlds[s][c * 512 + ((ks ^ (c & 7)) * 8)] = v;
  }
  float b1v = b1[col0 + rsel];
  __syncthreads();

  const int rbase = rowstart + ksl * 4;
  const size_t hrow = (size_t)(rowstart + rsel) * HIDN;

  f16x8 hf[16];   // h0(p-1) after MAIN(p); h0(p-2) during SHADOW(p)
  f32x4 part1;

  for (int p = 0; p <= S_LEN + 1; ++p) {
    const bool doH0 = (p <= S_LEN - 1);
    const bool doH1 = (p >= 2);

    // ---- SHADOW (only barrier(p-2)-published data; runs while others arrive) ----
    if (doH1) {
      f32x4 t = {b1v, b1v, b1v, b1v};
#pragma unroll
      for (int kt = 0; kt < 16; ++kt) {
        int ks = kt * 4 + ksl;
        f16x8 b = *(const f16x8*)&wlds[1][rsel * 512 + ((ks ^ (rsel & 7)) * 8)];
        t = __builtin_amdgcn_mfma_f32_16x16x32_f16(hf[kt], b, t, 0, 0, 0);
      }
      part1 = t;
    }
    f32x4 p0acc;
    if (doH0) {
#pragma unroll
      for (int j = 0; j < 4; ++j) {
        int t_ = tok[p * B_SZ + rbase + j];
        p0acc[j] = (float)P0h[(size_t)t_ * HIDN + col0 + rsel];
      }
    }

    // ---- WAIT barrier(p-1): relaxed polls, no per-iteration fences ----
    if (p >= 1) {
      if (tid == 0) {
        unsigned tgt = (unsigned)(NBLK * p);
        while (__hip_atomic_load(cnt, __ATOMIC_RELAXED, __HIP_MEMORY_SCOPE_AGENT) < tgt) {}
      }
      __syncthreads();
    }

    // ---- MAIN ----
    if (p <= S_LEN) {   // load h0(p-1) (slot 3 = init at p=0); also feeds SHADOW(p+1)
      const f16* src = h0ring + (size_t)((p - 1) & 3) * B_SZ * HIDN;
#pragma unroll
      for (int kt = 0; kt < 16; ++kt)
        hf[kt] = cload16(src + hrow + kt * 32 + ksl * 8);
    }
    if (doH0) {
      f32x4 acc0 = p0acc;
#pragma unroll
      for (int kt = 0; kt < 16; ++kt) {
        int ks = kt * 4 + ksl;
        f16x8 b = *(const f16x8*)&wlds[0][rsel * 512 + ((ks ^ (rsel & 7)) * 8)];
        acc0 = __builtin_amdgcn_mfma_f32_16x16x32_f16(hf[kt], b, acc0, 0, 0, 0);
      }
      f16* dst = h0ring + (size_t)(p & 3) * B_SZ * HIDN;
#pragma unroll
      for (int j = 0; j < 4; ++j) {
        float v = fast_tanh(acc0[j]);
        int r = rbase + j;
        cstore2(&dst[(size_t)r * HIDN + col0 + rsel], v);
        if (p == S_LEN - 1) outHid[(size_t)r * HIDN + col0 + rsel] = v;
      }
    }
    if (doH1) {
      const f16* h1src = (p == 2) ? h1init : H1 + (size_t)(p - 3) * B_SZ * HIDN;
      f16x8 h1f[16];
#pragma unroll
      for (int kt = 0; kt < 16; ++kt)
        h1f[kt] = cload16(h1src + hrow + kt * 32 + ksl * 8);
      f32x4 acc1 = part1;
#pragma unroll
      for (int kt = 0; kt < 16; ++kt) {
        int ks = kt * 4 + ksl;
        f16x8 b = *(const f16x8*)&wlds[2][rsel * 512 + ((ks ^ (rsel & 7)) * 8)];
        acc1 = __builtin_amdgcn_mfma_f32_16x16x32_f16(h1f[kt], b, acc1, 0, 0, 0);
      }
      f16* h1dst = H1 + (size_t)(p - 2) * B_SZ * HIDN;
#pragma unroll
      for (int j = 0; j < 4; ++j) {
        float v = fast_tanh(acc1[j]);
        int r = rbase + j;
        cstore2(&h1dst[(size_t)r * HIDN + col0 + rsel], v);
        if (p == S_LEN + 1) outHid[(size_t)(B_SZ * HIDN) + (size_t)r * HIDN + col0 + rsel] = v;
      }
    }

    // ---- ARRIVE barrier(p): drain write-through stores, one release add ----
    if (p <= S_LEN) {
      asm volatile("s_waitcnt vmcnt(0)" ::: "memory");
      __syncthreads();
      if (tid == 0)
        __hip_atomic_fetch_add(cnt, 1u, __ATOMIC_RELEASE, __HIP_MEMORY_SCOPE_AGENT);
    }
  }
}

extern "C" void kernel_launch(void* const* d_in, const int* in_sizes, int n_in,
                              void* d_out, int out_size, void* d_ws, size_t ws_size,
                              hipStream_t stream) {
  (void)in_sizes; (void)n_in; (void)out_size; (void)ws_size;
  const int*   tok    = (const int*)d_in[0];
  const float* hidden = (const float*)d_in[1];
  const float* emb    = (const float*)d_in[2];
  const float* W0     = (const float*)d_in[3];
  const float* b0     = (const float*)d_in[4];
  const float* W1     = (const float*)d_in[5];
  const float* b1     = (const float*)d_in[6];
  const float* Wout   = (const float*)d_in[7];
  const float* bout   = (const float*)d_in[8];

  char* ws = (char*)d_ws;
  size_t off = 0;
  f16* embf16  = (f16*)(ws + off); off += (size_t)VPAD * 512 * 2;   // zero-padded emb
  f16* woutf16 = (f16*)(ws + off); off += (size_t)VPAD * 512 * 2;   // zero-padded Wout
  f16* w0xf16  = (f16*)(ws + off); off += (size_t)512 * 512 * 2;    // W0[:, :512] packed
  f16* P0h     = (f16*)(ws + off); off += (size_t)VOC * 512 * 2;    // emb@W0x^T + b0
  f16* H1      = (f16*)(ws + off); off += (size_t)S_LEN * B_SZ * 512 * 2;
  f16* h0ring  = (f16*)(ws + off); off += (size_t)4 * B_SZ * 512 * 2;
  f16* h1init  = (f16*)(ws + off); off += (size_t)B_SZ * 512 * 2;
  unsigned* cnt = (unsigned*)(ws + off); off += 64;                  // barrier counter

  float* outHid = (float*)d_out + (size_t)S_LEN * B_SZ * VOC;

  hipMemsetAsync(cnt, 0, 4, stream);   // reset barrier each launch (capture-safe)

  int tot = VPAD * 512;
  convert_pad<<<(tot + 255) / 256, 256, 0, stream>>>(emb,  embf16,  VOC, 512, tot);
  convert_pad<<<(tot + 255) / 256, 256, 0, stream>>>(Wout, woutf16, VOC, 512, tot);
  tot = 512 * 512;
  convert_pad<<<(tot + 255) / 256, 256, 0, stream>>>(W0, w0xf16, 512, 1024, tot);
  tot = B_SZ * 512;
  convert_pad<<<(tot + 255) / 256, 256, 0, stream>>>(hidden, h0ring + (size_t)3 * B_SZ * 512, B_SZ, 512, tot);
  convert_pad<<<(tot + 255) / 256, 256, 0, stream>>>(hidden + (size_t)B_SZ * 512, h1init, B_SZ, 512, tot);

  // P0 = emb @ W0x^T + b0  (f16 out, [10000][512])
  gemm_k512<f16><<<dim3(4, VPAD / 128), 256, 0, stream>>>(
      embf16, w0xf16, P0h, b0, VOC, 512, 512);

  // recurrence (cooperative for co-residency; fence-free barrier inside)
  {
    void* args[] = {(void*)&tok, (void*)&W0, (void*)&W1, (void*)&b1, (void*)&P0h,
                    (void*)&h0ring, (void*)&h1init, (void*)&H1, (void*)&outHid, (void*)&cnt};
    hipLaunchCooperativeKernel((const void*)rnn_recur, dim3(NBLK), dim3(256), args, 0, stream);
  }

  // logits = H1 @ Wout^T + bout  -> d_out [16384][10000] fp32
  gemm_k512<float><<<dim3(79, 128), 256, 0, stream>>>(
      H1, woutf16, (float*)d_out, bout, S_LEN * B_SZ, VOC, VOC);
}

// Round 5
// 1300.158 us; speedup vs baseline: 1.9095x; 1.3076x over previous
//
#include <hip/hip_runtime.h>
#include <hip/hip_fp16.h>

typedef _Float16 f16;
typedef _Float16 f16x4 __attribute__((ext_vector_type(4)));
typedef _Float16 f16x8 __attribute__((ext_vector_type(8)));
typedef float f32x4 __attribute__((ext_vector_type(4)));
typedef unsigned u32x4 __attribute__((ext_vector_type(4)));

#define S_LEN 128
#define B_SZ  128
#define VOC   10000
#define VPAD  10240
#define HIDN  512
#define NBLK  64

__device__ __forceinline__ void gload_lds16(const void* g, void* l) {
  __builtin_amdgcn_global_load_lds(
      (const __attribute__((address_space(1))) void*)g,
      (__attribute__((address_space(3))) void*)l, 16, 0, 0);
}

// device-scope (coherence-point) 16B load: bypasses non-coherent caches.
// NOTE: consumer must s_waitcnt vmcnt + sched_barrier before use (rule #18).
__device__ __forceinline__ f16x8 ld16_dev(const f16* p) {
  u32x4 r;
  asm volatile("global_load_dwordx4 %0, %1, off sc1" : "=v"(r) : "v"(p));
  return __builtin_bit_cast(f16x8, r);
}
// write-through device-scope 2B store
__device__ __forceinline__ void cstore2(f16* p, float v) {
  f16 h = (f16)v;
  unsigned short u = __builtin_bit_cast(unsigned short, h);
  __hip_atomic_store((unsigned short*)p, u, __ATOMIC_RELAXED, __HIP_MEMORY_SCOPE_AGENT);
}

// tanh via v_exp + v_rcp
__device__ __forceinline__ float fast_tanh(float x) {
  float cx = fminf(8.f, fmaxf(-8.f, x));
  float e = __expf(2.f * cx);
  float d = e + 1.f, r;
  asm("v_rcp_f32 %0, %1" : "=v"(r) : "v"(d));
  return (e - 1.f) * r;
}

// ---- fp32 -> f16 convert, 512 cols, with zero row padding ----
__global__ void convert_pad(const float* __restrict__ src, f16* __restrict__ dst,
                            int rows, int src_stride, int total) {
  int idx = blockIdx.x * 256 + threadIdx.x;
  if (idx >= total) return;
  int r = idx >> 9, c = idx & 511;
  float v = (r < rows) ? src[(size_t)r * src_stride + c] : 0.f;
  dst[idx] = (f16)v;
}

// ---- GEMM: C[M][ldc] = A[*][512] . B[*][512]^T + bias[col]; 128x128 tiles, K=512 ----
template <typename CT>
__global__ __launch_bounds__(256) void gemm_k512(
    const f16* __restrict__ A, const f16* __restrict__ B,
    CT* __restrict__ C, const float* __restrict__ bias,
    int M, int N, int ldc)
{
  __shared__ f16 Asw[128 * 32];
  __shared__ f16 Bsw[128 * 32];
  const int tid  = threadIdx.x;
  const int lane = tid & 63, w = tid >> 6;
  const int wrow = w >> 1, wcol = w & 1;
  int nwg  = gridDim.x * gridDim.y;
  int orig = blockIdx.y * gridDim.x + blockIdx.x;
  int cpx  = nwg >> 3;
  int swz  = (orig & 7) * cpx + (orig >> 3);
  const int m0 = (swz / gridDim.x) * 128, n0 = (swz % gridDim.x) * 128;
  const int rsel = lane & 15, ksl = lane >> 4;

  f32x4 acc[4][4] = {};

  for (int kt = 0; kt < 16; ++kt) {
    __syncthreads();
#pragma unroll
    for (int i = 0; i < 2; ++i) {
      int c   = (i * 4 + w) * 64 + lane;
      int row = c >> 2, sp = c & 3;
      int sl  = sp ^ ((row >> 1) & 3);
      gload_lds16(A + (size_t)(m0 + row) * 512 + kt * 32 + sl * 8,
                  &Asw[(i * 4 + w) * 512]);
      gload_lds16(B + (size_t)(n0 + row) * 512 + kt * 32 + sl * 8,
                  &Bsw[(i * 4 + w) * 512]);
    }
    __syncthreads();
    f16x8 af[4], bf[4];
#pragma unroll
    for (int i = 0; i < 4; ++i) {
      int ar = wrow * 64 + i * 16 + rsel;
      af[i] = *(const f16x8*)&Asw[ar * 32 + ((ksl ^ ((ar >> 1) & 3)) * 8)];
      int br = wcol * 64 + i * 16 + rsel;
      bf[i] = *(const f16x8*)&Bsw[br * 32 + ((ksl ^ ((br >> 1) & 3)) * 8)];
    }
#pragma unroll
    for (int i = 0; i < 4; ++i)
#pragma unroll
      for (int j = 0; j < 4; ++j)
        acc[i][j] = __builtin_amdgcn_mfma_f32_16x16x32_f16(af[i], bf[j], acc[i][j], 0, 0, 0);
  }

#pragma unroll
  for (int tc = 0; tc < 4; ++tc) {
    int col = n0 + wcol * 64 + tc * 16 + rsel;
    if (col >= N) continue;
    float bv = bias ? bias[col] : 0.f;
#pragma unroll
    for (int i = 0; i < 4; ++i) {
      int rowb = m0 + wrow * 64 + i * 16 + ksl * 4;
#pragma unroll
      for (int j = 0; j < 4; ++j) {
        int row = rowb + j;
        if (row < M) C[(size_t)row * ldc + col] = (CT)(acc[i][tc][j] + bv);
      }
    }
  }
}

// ---- cooperative recurrence, shadow-pipelined (R3 structure) ----
// phase p (0..129):
//   SHADOW:  part1 = b1 + W1a@h0(p-2)  [registers]; P0 token gather
//   WAIT barrier(p-1)  [relaxed polls]
//   MAIN:    load hf=h0(p-1), h1f=h1(p-3) [dwordx4 sc1];
//            h0(p)=tanh(P0+W0h@hf); h1(p-2)=tanh(part1+W1b@h1f)
//   ARRIVE:  vmcnt(0) drain; syncthreads; tid0 RELAXED fetch_add
//            (release-fence redundant: all cross-block stores are sc1
//             write-through and drained — avoids per-phase buffer_wbl2)
__global__ __launch_bounds__(256, 1) void rnn_recur(
    const int* __restrict__ tok,    // [128][128]
    const float* __restrict__ W0,   // [512][1024]
    const float* __restrict__ W1,   // [512][1024]
    const float* __restrict__ b1,   // [512]
    const f16* __restrict__ P0h,    // [10000][512]  emb@W0x^T + b0
    f16* __restrict__ h0ring,       // [4][128][512] (slot 3 = initial h0)
    const f16* __restrict__ h1init, // [128][512]
    f16* __restrict__ H1,           // [128][128][512]
    float* __restrict__ outHid,     // [2][128][512] (d_out tail)
    unsigned* __restrict__ cnt)     // barrier counter (reset to 0 each launch)
{
  __shared__ f16 wlds[3][16 * 512];   // W0h^T, W1a^T, W1b^T column slices, XOR-swizzled
  const int tid = threadIdx.x;
  const int lane = tid & 63, w = tid >> 6;
  const int cgI = blockIdx.x & 31, bg = blockIdx.x >> 5;
  const int col0 = cgI * 16;
  const int rowstart = bg * 64 + w * 16;
  const int rsel = lane & 15, ksl = lane >> 4;

  for (int it = tid; it < 3 * 16 * 64; it += 256) {
    int s = it >> 10;
    int rem = it & 1023;
    int c = rem >> 6, ks = rem & 63;
    int n = col0 + c;
    const float* srcp;
    if (s == 0)      srcp = W0 + (size_t)n * 1024 + 512 + ks * 8;  // W0h
    else if (s == 1) srcp = W1 + (size_t)n * 1024 + ks * 8;        // W1a
    else             srcp = W1 + (size_t)n * 1024 + 512 + ks * 8;  // W1b
    f16x8 v;
#pragma unroll
    for (int j = 0; j < 8; ++j) v[j] = (f16)srcp[j];
    *(f16x8*)&wlds[s][c * 512 + ((ks ^ (c & 7)) * 8)] = v;
  }
  float b1v = b1[col0 + rsel];
  __syncthreads();

  const int rbase = rowstart + ksl * 4;
  const size_t hrow = (size_t)(rowstart + rsel) * HIDN;

  f16x8 hf[16];   // h0(p-1) after MAIN(p); h0(p-2) during SHADOW(p)
  f32x4 part1;

  for (int p = 0; p <= S_LEN + 1; ++p) {
    const bool doH0 = (p <= S_LEN - 1);
    const bool doH1 = (p >= 2);

    // ---- SHADOW ----
    if (doH1) {
      f32x4 t = {b1v, b1v, b1v, b1v};
#pragma unroll
      for (int kt = 0; kt < 16; ++kt) {
        int ks = kt * 4 + ksl;
        f16x8 b = *(const f16x8*)&wlds[1][rsel * 512 + ((ks ^ (rsel & 7)) * 8)];
        t = __builtin_amdgcn_mfma_f32_16x16x32_f16(hf[kt], b, t, 0, 0, 0);
      }
      part1 = t;
    }
    f32x4 p0acc;
    if (doH0) {
#pragma unroll
      for (int j = 0; j < 4; ++j) {
        int t_ = tok[p * B_SZ + rbase + j];
        p0acc[j] = (float)P0h[(size_t)t_ * HIDN + col0 + rsel];
      }
    }

    // ---- WAIT barrier(p-1): relaxed polls ----
    if (p >= 1) {
      if (tid == 0) {
        unsigned tgt = (unsigned)(NBLK * p);
        while (__hip_atomic_load(cnt, __ATOMIC_RELAXED, __HIP_MEMORY_SCOPE_AGENT) < tgt) {}
      }
      __syncthreads();
    }

    // ---- MAIN: issue all device-scope loads, one drain, then MFMA ----
    if (p <= S_LEN) {
      const f16* src = h0ring + (size_t)((p - 1) & 3) * B_SZ * HIDN;
#pragma unroll
      for (int kt = 0; kt < 16; ++kt)
        hf[kt] = ld16_dev(src + hrow + kt * 32 + ksl * 8);
    }
    f16x8 h1f[16];
    if (doH1) {
      const f16* h1src = (p == 2) ? h1init : H1 + (size_t)(p - 3) * B_SZ * HIDN;
#pragma unroll
      for (int kt = 0; kt < 16; ++kt)
        h1f[kt] = ld16_dev(h1src + hrow + kt * 32 + ksl * 8);
    }
    asm volatile("s_waitcnt vmcnt(0)" ::: "memory");
    __builtin_amdgcn_sched_barrier(0);

    if (doH0) {
      f32x4 acc0 = p0acc;
#pragma unroll
      for (int kt = 0; kt < 16; ++kt) {
        int ks = kt * 4 + ksl;
        f16x8 b = *(const f16x8*)&wlds[0][rsel * 512 + ((ks ^ (rsel & 7)) * 8)];
        acc0 = __builtin_amdgcn_mfma_f32_16x16x32_f16(hf[kt], b, acc0, 0, 0, 0);
      }
      f16* dst = h0ring + (size_t)(p & 3) * B_SZ * HIDN;
#pragma unroll
      for (int j = 0; j < 4; ++j) {
        float v = fast_tanh(acc0[j]);
        int r = rbase + j;
        cstore2(&dst[(size_t)r * HIDN + col0 + rsel], v);
        if (p == S_LEN - 1) outHid[(size_t)r * HIDN + col0 + rsel] = v;
      }
    }
    if (doH1) {
      f32x4 acc1 = part1;
#pragma unroll
      for (int kt = 0; kt < 16; ++kt) {
        int ks = kt * 4 + ksl;
        f16x8 b = *(const f16x8*)&wlds[2][rsel * 512 + ((ks ^ (rsel & 7)) * 8)];
        acc1 = __builtin_amdgcn_mfma_f32_16x16x32_f16(h1f[kt], b, acc1, 0, 0, 0);
      }
      f16* h1dst = H1 + (size_t)(p - 2) * B_SZ * HIDN;
#pragma unroll
      for (int j = 0; j < 4; ++j) {
        float v = fast_tanh(acc1[j]);
        int r = rbase + j;
        cstore2(&h1dst[(size_t)r * HIDN + col0 + rsel], v);
        if (p == S_LEN + 1) outHid[(size_t)(B_SZ * HIDN) + (size_t)r * HIDN + col0 + rsel] = v;
      }
    }

    // ---- ARRIVE barrier(p) ----
    if (p <= S_LEN) {
      asm volatile("s_waitcnt vmcnt(0)" ::: "memory");
      __syncthreads();
      if (tid == 0)
        __hip_atomic_fetch_add(cnt, 1u, __ATOMIC_RELAXED, __HIP_MEMORY_SCOPE_AGENT);
    }
  }
}

extern "C" void kernel_launch(void* const* d_in, const int* in_sizes, int n_in,
                              void* d_out, int out_size, void* d_ws, size_t ws_size,
                              hipStream_t stream) {
  (void)in_sizes; (void)n_in; (void)out_size; (void)ws_size;
  const int*   tok    = (const int*)d_in[0];
  const float* hidden = (const float*)d_in[1];
  const float* emb    = (const float*)d_in[2];
  const float* W0     = (const float*)d_in[3];
  const float* b0     = (const float*)d_in[4];
  const float* W1     = (const float*)d_in[5];
  const float* b1     = (const float*)d_in[6];
  const float* Wout   = (const float*)d_in[7];
  const float* bout   = (const float*)d_in[8];

  char* ws = (char*)d_ws;
  size_t off = 0;
  f16* embf16  = (f16*)(ws + off); off += (size_t)VPAD * 512 * 2;
  f16* woutf16 = (f16*)(ws + off); off += (size_t)VPAD * 512 * 2;
  f16* w0xf16  = (f16*)(ws + off); off += (size_t)512 * 512 * 2;
  f16* P0h     = (f16*)(ws + off); off += (size_t)VOC * 512 * 2;
  f16* H1      = (f16*)(ws + off); off += (size_t)S_LEN * B_SZ * 512 * 2;
  f16* h0ring  = (f16*)(ws + off); off += (size_t)4 * B_SZ * 512 * 2;
  f16* h1init  = (f16*)(ws + off); off += (size_t)B_SZ * 512 * 2;
  unsigned* cnt = (unsigned*)(ws + off); off += 64;

  float* outHid = (float*)d_out + (size_t)S_LEN * B_SZ * VOC;

  hipMemsetAsync(cnt, 0, 4, stream);   // reset barrier each launch (capture-safe)

  int tot = VPAD * 512;
  convert_pad<<<(tot + 255) / 256, 256, 0, stream>>>(emb,  embf16,  VOC, 512, tot);
  convert_pad<<<(tot + 255) / 256, 256, 0, stream>>>(Wout, woutf16, VOC, 512, tot);
  tot = 512 * 512;
  convert_pad<<<(tot + 255) / 256, 256, 0, stream>>>(W0, w0xf16, 512, 1024, tot);
  tot = B_SZ * 512;
  convert_pad<<<(tot + 255) / 256, 256, 0, stream>>>(hidden, h0ring + (size_t)3 * B_SZ * 512, B_SZ, 512, tot);
  convert_pad<<<(tot + 255) / 256, 256, 0, stream>>>(hidden + (size_t)B_SZ * 512, h1init, B_SZ, 512, tot);

  // P0 = emb @ W0x^T + b0  (f16 out, [10000][512])
  gemm_k512<f16><<<dim3(4, VPAD / 128), 256, 0, stream>>>(
      embf16, w0xf16, P0h, b0, VOC, 512, 512);

  // recurrence (cooperative for co-residency; fence-free barrier inside)
  {
    void* args[] = {(void*)&tok, (void*)&W0, (void*)&W1, (void*)&b1, (void*)&P0h,
                    (void*)&h0ring, (void*)&h1init, (void*)&H1, (void*)&outHid, (void*)&cnt};
    hipLaunchCooperativeKernel((const void*)rnn_recur, dim3(NBLK), dim3(256), args, 0, stream);
  }

  // logits = H1 @ Wout^T + bout  -> d_out [16384][10000] fp32
  gemm_k512<float><<<dim3(79, 128), 256, 0, stream>>>(
      H1, woutf16, (float*)d_out, bout, S_LEN * B_SZ, VOC, VOC);
}

// Round 6
// 1205.055 us; speedup vs baseline: 2.0602x; 1.0789x over previous
//
#include <hip/hip_runtime.h>
#include <hip/hip_fp16.h>

typedef _Float16 f16;
typedef _Float16 f16x4 __attribute__((ext_vector_type(4)));
typedef _Float16 f16x8 __attribute__((ext_vector_type(8)));
typedef float f32x4 __attribute__((ext_vector_type(4)));
typedef unsigned u32x4 __attribute__((ext_vector_type(4)));

#define S_LEN 128
#define B_SZ  128
#define VOC   10000
#define VPAD  10240
#define HIDN  512
#define NBLK  64
#define NFLAG (NBLK * 4)   // per-wave flags

// counted waitcnt + scheduler fence (rule #18)
#define VMCNT(n) do { asm volatile("s_waitcnt vmcnt(" #n ")" ::: "memory"); \
                      __builtin_amdgcn_sched_barrier(0); } while (0)

__device__ __forceinline__ void gload_lds16(const void* g, void* l) {
  __builtin_amdgcn_global_load_lds(
      (const __attribute__((address_space(1))) void*)g,
      (__attribute__((address_space(3))) void*)l, 16, 0, 0);
}

// device-scope (coherence-point) 16B load; consumer must VMCNT before use
__device__ __forceinline__ f16x8 ld16_dev(const f16* p) {
  u32x4 r;
  asm volatile("global_load_dwordx4 %0, %1, off sc1" : "=v"(r) : "v"(p));
  return __builtin_bit_cast(f16x8, r);
}
// write-through device-scope 2B store
__device__ __forceinline__ void cstore2(f16* p, float v) {
  f16 h = (f16)v;
  unsigned short u = __builtin_bit_cast(unsigned short, h);
  __hip_atomic_store((unsigned short*)p, u, __ATOMIC_RELAXED, __HIP_MEMORY_SCOPE_AGENT);
}
// device-scope flag store (plain store, no RMW)
__device__ __forceinline__ void stflag_dev(unsigned* p, unsigned v) {
  asm volatile("global_store_dword %0, %1, off sc1" :: "v"(p), "v"(v) : "memory");
}

// tanh via v_exp + v_rcp
__device__ __forceinline__ float fast_tanh(float x) {
  float cx = fminf(8.f, fmaxf(-8.f, x));
  float e = __expf(2.f * cx);
  float d = e + 1.f, r;
  asm("v_rcp_f32 %0, %1" : "=v"(r) : "v"(d));
  return (e - 1.f) * r;
}

// ---- fp32 -> f16 convert, 512 cols, with zero row padding ----
__global__ void convert_pad(const float* __restrict__ src, f16* __restrict__ dst,
                            int rows, int src_stride, int total) {
  int idx = blockIdx.x * 256 + threadIdx.x;
  if (idx >= total) return;
  int r = idx >> 9, c = idx & 511;
  float v = (r < rows) ? src[(size_t)r * src_stride + c] : 0.f;
  dst[idx] = (f16)v;
}

// ---- GEMM: C[M][ldc] = A[*][512] . B[*][512]^T + bias[col]; 128x128 tiles, K=512 ----
template <typename CT>
__global__ __launch_bounds__(256) void gemm_k512(
    const f16* __restrict__ A, const f16* __restrict__ B,
    CT* __restrict__ C, const float* __restrict__ bias,
    int M, int N, int ldc)
{
  __shared__ f16 Asw[128 * 32];
  __shared__ f16 Bsw[128 * 32];
  const int tid  = threadIdx.x;
  const int lane = tid & 63, w = tid >> 6;
  const int wrow = w >> 1, wcol = w & 1;
  int nwg  = gridDim.x * gridDim.y;
  int orig = blockIdx.y * gridDim.x + blockIdx.x;
  int cpx  = nwg >> 3;
  int swz  = (orig & 7) * cpx + (orig >> 3);
  const int m0 = (swz / gridDim.x) * 128, n0 = (swz % gridDim.x) * 128;
  const int rsel = lane & 15, ksl = lane >> 4;

  f32x4 acc[4][4] = {};

  for (int kt = 0; kt < 16; ++kt) {
    __syncthreads();
#pragma unroll
    for (int i = 0; i < 2; ++i) {
      int c   = (i * 4 + w) * 64 + lane;
      int row = c >> 2, sp = c & 3;
      int sl  = sp ^ ((row >> 1) & 3);
      gload_lds16(A + (size_t)(m0 + row) * 512 + kt * 32 + sl * 8,
                  &Asw[(i * 4 + w) * 512]);
      gload_lds16(B + (size_t)(n0 + row) * 512 + kt * 32 + sl * 8,
                  &Bsw[(i * 4 + w) * 512]);
    }
    __syncthreads();
    f16x8 af[4], bf[4];
#pragma unroll
    for (int i = 0; i < 4; ++i) {
      int ar = wrow * 64 + i * 16 + rsel;
      af[i] = *(const f16x8*)&Asw[ar * 32 + ((ksl ^ ((ar >> 1) & 3)) * 8)];
      int br = wcol * 64 + i * 16 + rsel;
      bf[i] = *(const f16x8*)&Bsw[br * 32 + ((ksl ^ ((br >> 1) & 3)) * 8)];
    }
#pragma unroll
    for (int i = 0; i < 4; ++i)
#pragma unroll
      for (int j = 0; j < 4; ++j)
        acc[i][j] = __builtin_amdgcn_mfma_f32_16x16x32_f16(af[i], bf[j], acc[i][j], 0, 0, 0);
  }

#pragma unroll
  for (int tc = 0; tc < 4; ++tc) {
    int col = n0 + wcol * 64 + tc * 16 + rsel;
    if (col >= N) continue;
    float bv = bias ? bias[col] : 0.f;
#pragma unroll
    for (int i = 0; i < 4; ++i) {
      int rowb = m0 + wrow * 64 + i * 16 + ksl * 4;
#pragma unroll
      for (int j = 0; j < 4; ++j) {
        int row = rowb + j;
        if (row < M) C[(size_t)row * ldc + col] = (CT)(acc[i][tc][j] + bv);
      }
    }
  }
}

// ---- cooperative recurrence, shadow-pipelined, wave-autonomous flag sync ----
// phase p (0..129):
//   SHADOW: part1 = b1 + W1a@h0(p-2) [regs]; P0 gather (pinned)
//   WAIT:   poll 256 per-wave flags >= p (64-lane dwordx4, no RMW, no fences)
//   MAIN:   issue hf=h0(p-1) loads, h1f=h1(p-3) loads;
//           vmcnt(16) -> W0h MFMA + tanh + h0 stores (h1f still in flight);
//           vmcnt(8)  -> W1b MFMA + tanh + h1 stores;
//   ARRIVE: vmcnt(0); lane0 stores own wave flag = p+1 (plain sc1 store)
__global__ __launch_bounds__(256, 1) void rnn_recur(
    const int* __restrict__ tok,    // [128][128]
    const float* __restrict__ W0,   // [512][1024]
    const float* __restrict__ W1,   // [512][1024]
    const float* __restrict__ b1,   // [512]
    const f16* __restrict__ P0h,    // [10000][512]  emb@W0x^T + b0
    f16* __restrict__ h0ring,       // [4][128][512] (slot 3 = initial h0)
    const f16* __restrict__ h1init, // [128][512]
    f16* __restrict__ H1,           // [128][128][512]
    float* __restrict__ outHid,     // [2][128][512] (d_out tail)
    unsigned* __restrict__ flags)   // [256] per-wave flags (zeroed each launch)
{
  __shared__ f16 wlds[3][16 * 512];   // W0h^T, W1a^T, W1b^T column slices, XOR-swizzled
  const int tid = threadIdx.x;
  const int lane = tid & 63, w = tid >> 6;
  const int cgI = blockIdx.x & 31, bg = blockIdx.x >> 5;
  const int col0 = cgI * 16;
  const int rowstart = bg * 64 + w * 16;
  const int rsel = lane & 15, ksl = lane >> 4;
  const int fidx = blockIdx.x * 4 + w;

  for (int it = tid; it < 3 * 16 * 64; it += 256) {
    int s = it >> 10;
    int rem = it & 1023;
    int c = rem >> 6, ks = rem & 63;
    int n = col0 + c;
    const float* srcp;
    if (s == 0)      srcp = W0 + (size_t)n * 1024 + 512 + ks * 8;  // W0h
    else if (s == 1) srcp = W1 + (size_t)n * 1024 + ks * 8;        // W1a
    else             srcp = W1 + (size_t)n * 1024 + 512 + ks * 8;  // W1b
    f16x8 v;
#pragma unroll
    for (int j = 0; j < 8; ++j) v[j] = (f16)srcp[j];
    *(f16x8*)&wlds[s][c * 512 + ((ks ^ (c & 7)) * 8)] = v;
  }
  float b1v = b1[col0 + rsel];
  __syncthreads();   // weights visible to all waves; after this, waves are autonomous

  const int rbase = rowstart + ksl * 4;
  const size_t hrow = (size_t)(rowstart + rsel) * HIDN;
  const unsigned* fptr = flags + 4 * lane;

  f16x8 hf[16];   // h0(p-1) after MAIN(p); h0(p-2) during SHADOW(p)
  f32x4 part1;

  for (int p = 0; p <= S_LEN + 1; ++p) {
    const bool doH0 = (p <= S_LEN - 1);
    const bool doH1 = (p >= 2);

    // ---- SHADOW ----
    if (doH1) {
      f32x4 t = {b1v, b1v, b1v, b1v};
#pragma unroll
      for (int kt = 0; kt < 16; ++kt) {
        int ks = kt * 4 + ksl;
        f16x8 b = *(const f16x8*)&wlds[1][rsel * 512 + ((ks ^ (rsel & 7)) * 8)];
        t = __builtin_amdgcn_mfma_f32_16x16x32_f16(hf[kt], b, t, 0, 0, 0);
      }
      part1 = t;
    }
    float pa0, pa1, pa2, pa3;
    if (doH0) {
      const int tbase = p * B_SZ + rbase;
      pa0 = (float)P0h[(size_t)tok[tbase + 0] * HIDN + col0 + rsel];
      pa1 = (float)P0h[(size_t)tok[tbase + 1] * HIDN + col0 + rsel];
      pa2 = (float)P0h[(size_t)tok[tbase + 2] * HIDN + col0 + rsel];
      pa3 = (float)P0h[(size_t)tok[tbase + 3] * HIDN + col0 + rsel];
      // pin: force gather completion here so compiler waitcnts stay out of MAIN
      asm volatile("" : "+v"(pa0), "+v"(pa1), "+v"(pa2), "+v"(pa3));
    }

    // ---- WAIT: all 256 wave-flags >= p ----
    if (p >= 1) {
      const unsigned tgt = (unsigned)p;
      for (;;) {
        u32x4 f;
        asm volatile("global_load_dwordx4 %0, %1, off sc1\n\ts_waitcnt vmcnt(0)"
                     : "=v"(f) : "v"(fptr) : "memory");
        int ok = (f[0] >= tgt) & (f[1] >= tgt) & (f[2] >= tgt) & (f[3] >= tgt);
        if (__all(ok)) break;
      }
    }

    // ---- MAIN: issue device-scope loads (hf first: critical path) ----
    if (p <= S_LEN) {
      const f16* src = h0ring + (size_t)((p - 1) & 3) * B_SZ * HIDN;
#pragma unroll
      for (int kt = 0; kt < 16; ++kt)
        hf[kt] = ld16_dev(src + hrow + kt * 32 + ksl * 8);
    }
    f16x8 h1f[16];
    if (doH1) {
      const f16* h1src = (p == 2) ? h1init : H1 + (size_t)(p - 3) * B_SZ * HIDN;
#pragma unroll
      for (int kt = 0; kt < 16; ++kt)
        h1f[kt] = ld16_dev(h1src + hrow + kt * 32 + ksl * 8);
    }

    if (doH0) {
      if (doH1) { VMCNT(16); } else { VMCNT(0); }   // hf ready; h1f may fly
      f32x4 acc0 = {pa0, pa1, pa2, pa3};
#pragma unroll
      for (int kt = 0; kt < 16; ++kt) {
        int ks = kt * 4 + ksl;
        f16x8 b = *(const f16x8*)&wlds[0][rsel * 512 + ((ks ^ (rsel & 7)) * 8)];
        acc0 = __builtin_amdgcn_mfma_f32_16x16x32_f16(hf[kt], b, acc0, 0, 0, 0);
      }
      f16* dst = h0ring + (size_t)(p & 3) * B_SZ * HIDN;
#pragma unroll
      for (int j = 0; j < 4; ++j) {
        float v = fast_tanh(acc0[j]);
        int r = rbase + j;
        cstore2(&dst[(size_t)r * HIDN + col0 + rsel], v);
        if (p == S_LEN - 1) outHid[(size_t)r * HIDN + col0 + rsel] = v;
      }
    }
    if (doH1) {
      if (doH0) { VMCNT(8); } else { VMCNT(0); }    // h1f (oldest 16) complete
      f32x4 acc1 = part1;
#pragma unroll
      for (int kt = 0; kt < 16; ++kt) {
        int ks = kt * 4 + ksl;
        f16x8 b = *(const f16x8*)&wlds[2][rsel * 512 + ((ks ^ (rsel & 7)) * 8)];
        acc1 = __builtin_amdgcn_mfma_f32_16x16x32_f16(h1f[kt], b, acc1, 0, 0, 0);
      }
      f16* h1dst = H1 + (size_t)(p - 2) * B_SZ * HIDN;
#pragma unroll
      for (int j = 0; j < 4; ++j) {
        float v = fast_tanh(acc1[j]);
        int r = rbase + j;
        cstore2(&h1dst[(size_t)r * HIDN + col0 + rsel], v);
        if (p == S_LEN + 1) outHid[(size_t)(B_SZ * HIDN) + (size_t)r * HIDN + col0 + rsel] = v;
      }
    }

    // ---- ARRIVE: per-wave drain + own-flag store ----
    if (p <= S_LEN) {
      VMCNT(0);
      if (lane == 0) stflag_dev((unsigned*)flags + fidx, (unsigned)(p + 1));
    }
  }
}

extern "C" void kernel_launch(void* const* d_in, const int* in_sizes, int n_in,
                              void* d_out, int out_size, void* d_ws, size_t ws_size,
                              hipStream_t stream) {
  (void)in_sizes; (void)n_in; (void)out_size; (void)ws_size;
  const int*   tok    = (const int*)d_in[0];
  const float* hidden = (const float*)d_in[1];
  const float* emb    = (const float*)d_in[2];
  const float* W0     = (const float*)d_in[3];
  const float* b0     = (const float*)d_in[4];
  const float* W1     = (const float*)d_in[5];
  const float* b1     = (const float*)d_in[6];
  const float* Wout   = (const float*)d_in[7];
  const float* bout   = (const float*)d_in[8];

  char* ws = (char*)d_ws;
  size_t off = 0;
  f16* embf16  = (f16*)(ws + off); off += (size_t)VPAD * 512 * 2;
  f16* woutf16 = (f16*)(ws + off); off += (size_t)VPAD * 512 * 2;
  f16* w0xf16  = (f16*)(ws + off); off += (size_t)512 * 512 * 2;
  f16* P0h     = (f16*)(ws + off); off += (size_t)VOC * 512 * 2;
  f16* H1      = (f16*)(ws + off); off += (size_t)S_LEN * B_SZ * 512 * 2;
  f16* h0ring  = (f16*)(ws + off); off += (size_t)4 * B_SZ * 512 * 2;
  f16* h1init  = (f16*)(ws + off); off += (size_t)B_SZ * 512 * 2;
  unsigned* flags = (unsigned*)(ws + off); off += NFLAG * 4;

  float* outHid = (float*)d_out + (size_t)S_LEN * B_SZ * VOC;

  hipMemsetAsync(flags, 0, NFLAG * 4, stream);   // reset flags each launch

  int tot = VPAD * 512;
  convert_pad<<<(tot + 255) / 256, 256, 0, stream>>>(emb,  embf16,  VOC, 512, tot);
  convert_pad<<<(tot + 255) / 256, 256, 0, stream>>>(Wout, woutf16, VOC, 512, tot);
  tot = 512 * 512;
  convert_pad<<<(tot + 255) / 256, 256, 0, stream>>>(W0, w0xf16, 512, 1024, tot);
  tot = B_SZ * 512;
  convert_pad<<<(tot + 255) / 256, 256, 0, stream>>>(hidden, h0ring + (size_t)3 * B_SZ * 512, B_SZ, 512, tot);
  convert_pad<<<(tot + 255) / 256, 256, 0, stream>>>(hidden + (size_t)B_SZ * 512, h1init, B_SZ, 512, tot);

  // P0 = emb @ W0x^T + b0  (f16 out, [10000][512])
  gemm_k512<f16><<<dim3(4, VPAD / 128), 256, 0, stream>>>(
      embf16, w0xf16, P0h, b0, VOC, 512, 512);

  // recurrence (cooperative for co-residency; wave-autonomous flag sync inside)
  {
    void* args[] = {(void*)&tok, (void*)&W0, (void*)&W1, (void*)&b1, (void*)&P0h,
                    (void*)&h0ring, (void*)&h1init, (void*)&H1, (void*)&outHid, (void*)&flags};
    hipLaunchCooperativeKernel((const void*)rnn_recur, dim3(NBLK), dim3(256), args, 0, stream);
  }

  // logits = H1 @ Wout^T + bout  -> d_out [16384][10000] fp32
  gemm_k512<float><<<dim3(79, 128), 256, 0, stream>>>(
      H1, woutf16, (float*)d_out, bout, S_LEN * B_SZ, VOC, VOC);
}

// Round 8
// 1180.177 us; speedup vs baseline: 2.1036x; 1.0211x over previous
//
#include <hip/hip_runtime.h>
#include <hip/hip_fp16.h>

typedef _Float16 f16;
typedef _Float16 f16x4 __attribute__((ext_vector_type(4)));
typedef _Float16 f16x8 __attribute__((ext_vector_type(8)));
typedef float f32x4 __attribute__((ext_vector_type(4)));
typedef unsigned u32x4 __attribute__((ext_vector_type(4)));

#define S_LEN 128
#define B_SZ  128
#define VOC   10000
#define VPAD  10240
#define HIDN  512
#define NBLK  64
#define NFLAG (NBLK * 4)   // per-wave flags

// counted waitcnt + scheduler fence (rule #18)
#define VMCNT(n) do { asm volatile("s_waitcnt vmcnt(" #n ")" ::: "memory"); \
                      __builtin_amdgcn_sched_barrier(0); } while (0)

__device__ __forceinline__ void gload_lds16(const void* g, void* l) {
  __builtin_amdgcn_global_load_lds(
      (const __attribute__((address_space(1))) void*)g,
      (__attribute__((address_space(3))) void*)l, 16, 0, 0);
}

// device-scope (coherence-point) 16B load; consumer must VMCNT before use
__device__ __forceinline__ f16x8 ld16_dev(const f16* p) {
  u32x4 r;
  asm volatile("global_load_dwordx4 %0, %1, off sc1" : "=v"(r) : "v"(p));
  return __builtin_bit_cast(f16x8, r);
}
// write-through device-scope 2B store
__device__ __forceinline__ void cstore2(f16* p, float v) {
  f16 h = (f16)v;
  unsigned short u = __builtin_bit_cast(unsigned short, h);
  __hip_atomic_store((unsigned short*)p, u, __ATOMIC_RELAXED, __HIP_MEMORY_SCOPE_AGENT);
}
// device-scope flag store (plain store, no RMW)
__device__ __forceinline__ void stflag_dev(unsigned* p, unsigned v) {
  asm volatile("global_store_dword %0, %1, off sc1" :: "v"(p), "v"(v) : "memory");
}

// tanh via v_exp + v_rcp
__device__ __forceinline__ float fast_tanh(float x) {
  float cx = fminf(8.f, fmaxf(-8.f, x));
  float e = __expf(2.f * cx);
  float d = e + 1.f, r;
  asm("v_rcp_f32 %0, %1" : "=v"(r) : "v"(d));
  return (e - 1.f) * r;
}

// ---- fp32 -> f16 convert, 512 cols, with zero row padding ----
__global__ void convert_pad(const float* __restrict__ src, f16* __restrict__ dst,
                            int rows, int src_stride, int total) {
  int idx = blockIdx.x * 256 + threadIdx.x;
  if (idx >= total) return;
  int r = idx >> 9, c = idx & 511;
  float v = (r < rows) ? src[(size_t)r * src_stride + c] : 0.f;
  dst[idx] = (f16)v;
}

// ---- GEMM: C[M][ldc] = A[*][512] . B[*][512]^T + bias[col]; 128x128 tiles, K=512 ----
// Swapped-operand MFMA (mfma(bf, af)) => each lane's acc quad = 4 CONSECUTIVE COLUMNS
// of one row -> vectorized dwordx4 C-stores (16 per thread vs 64 scalar).
template <typename CT>
__global__ __launch_bounds__(256) void gemm_k512(
    const f16* __restrict__ A, const f16* __restrict__ B,
    CT* __restrict__ C, const float* __restrict__ bias,
    int M, int N, int ldc)
{
  __shared__ f16 Asw[128 * 32];
  __shared__ f16 Bsw[128 * 32];
  const int tid  = threadIdx.x;
  const int lane = tid & 63, w = tid >> 6;
  const int wrow = w >> 1, wcol = w & 1;
  int nwg  = gridDim.x * gridDim.y;
  int orig = blockIdx.y * gridDim.x + blockIdx.x;
  int cpx  = nwg >> 3;
  int swz  = (orig & 7) * cpx + (orig >> 3);
  const int m0 = (swz / gridDim.x) * 128, n0 = (swz % gridDim.x) * 128;
  const int rsel = lane & 15, ksl = lane >> 4;

  f32x4 acc[4][4] = {};

  for (int kt = 0; kt < 16; ++kt) {
    __syncthreads();
#pragma unroll
    for (int i = 0; i < 2; ++i) {
      int c   = (i * 4 + w) * 64 + lane;
      int row = c >> 2, sp = c & 3;
      int sl  = sp ^ ((row >> 1) & 3);
      gload_lds16(A + (size_t)(m0 + row) * 512 + kt * 32 + sl * 8,
                  &Asw[(i * 4 + w) * 512]);
      gload_lds16(B + (size_t)(n0 + row) * 512 + kt * 32 + sl * 8,
                  &Bsw[(i * 4 + w) * 512]);
    }
    __syncthreads();
    f16x8 af[4], bf[4];
#pragma unroll
    for (int i = 0; i < 4; ++i) {
      int ar = wrow * 64 + i * 16 + rsel;
      af[i] = *(const f16x8*)&Asw[ar * 32 + ((ksl ^ ((ar >> 1) & 3)) * 8)];
      int br = wcol * 64 + i * 16 + rsel;
      bf[i] = *(const f16x8*)&Bsw[br * 32 + ((ksl ^ ((br >> 1) & 3)) * 8)];
    }
    // swapped operands: D = B-free (rows) x A-free (cols) => acc[i][j] holds
    // C[m = m0+wrow*64+i*16+rsel][n = n0+wcol*64+j*16+ksl*4 .. +3]
#pragma unroll
    for (int i = 0; i < 4; ++i)
#pragma unroll
      for (int j = 0; j < 4; ++j)
        acc[i][j] = __builtin_amdgcn_mfma_f32_16x16x32_f16(bf[j], af[i], acc[i][j], 0, 0, 0);
  }

#pragma unroll
  for (int i = 0; i < 4; ++i) {
    int row = m0 + wrow * 64 + i * 16 + rsel;
    if (row >= M) continue;
#pragma unroll
    for (int j = 0; j < 4; ++j) {
      int nb = n0 + wcol * 64 + j * 16 + ksl * 4;
      if (nb >= N) continue;        // N % 4 == 0 => whole quad in/out together
      f32x4 v = acc[i][j];
      if (bias) {
        f32x4 bv = *(const f32x4*)(bias + nb);
        v += bv;
      }
      if constexpr (__is_same(CT, float)) {
        *(f32x4*)&C[(size_t)row * ldc + nb] = v;
      } else {
        f16x4 hv;
#pragma unroll
        for (int q = 0; q < 4; ++q) hv[q] = (f16)v[q];
        *(f16x4*)&C[(size_t)row * ldc + nb] = hv;
      }
    }
  }
}

// ---- cooperative recurrence, shadow-pipelined, wave-autonomous flag sync (R6, proven) ----
// phase p (0..129):
//   SHADOW: part1 = b1 + W1a@h0(p-2) [regs]; P0 gather (pinned)
//   WAIT:   poll 256 per-wave flags >= p (64-lane dwordx4, no RMW, no fences)
//   MAIN:   issue hf=h0(p-1) loads, h1f=h1(p-3) loads;
//           vmcnt(16) -> W0h MFMA + tanh + h0 stores (h1f still in flight);
//           vmcnt(8)  -> W1b MFMA + tanh + h1 stores;
//   ARRIVE: vmcnt(0); lane0 stores own wave flag = p+1 (plain sc1 store)
__global__ __launch_bounds__(256, 1) void rnn_recur(
    const int* __restrict__ tok,    // [128][128]
    const float* __restrict__ W0,   // [512][1024]
    const float* __restrict__ W1,   // [512][1024]
    const float* __restrict__ b1,   // [512]
    const f16* __restrict__ P0h,    // [10000][512]  emb@W0x^T + b0
    f16* __restrict__ h0ring,       // [4][128][512] (slot 3 = initial h0)
    const f16* __restrict__ h1init, // [128][512]
    f16* __restrict__ H1,           // [128][128][512]
    float* __restrict__ outHid,     // [2][128][512] (d_out tail)
    unsigned* __restrict__ flags)   // [256] per-wave flags (zeroed each launch)
{
  __shared__ f16 wlds[3][16 * 512];   // W0h^T, W1a^T, W1b^T column slices, XOR-swizzled
  const int tid = threadIdx.x;
  const int lane = tid & 63, w = tid >> 6;
  const int cgI = blockIdx.x & 31, bg = blockIdx.x >> 5;
  const int col0 = cgI * 16;
  const int rowstart = bg * 64 + w * 16;
  const int rsel = lane & 15, ksl = lane >> 4;
  const int fidx = blockIdx.x * 4 + w;

  for (int it = tid; it < 3 * 16 * 64; it += 256) {
    int s = it >> 10;
    int rem = it & 1023;
    int c = rem >> 6, ks = rem & 63;
    int n = col0 + c;
    const float* srcp;
    if (s == 0)      srcp = W0 + (size_t)n * 1024 + 512 + ks * 8;  // W0h
    else if (s == 1) srcp = W1 + (size_t)n * 1024 + ks * 8;        // W1a
    else             srcp = W1 + (size_t)n * 1024 + 512 + ks * 8;  // W1b
    f16x8 v;
#pragma unroll
    for (int j = 0; j < 8; ++j) v[j] = (f16)srcp[j];
    *(f16x8*)&wlds[s][c * 512 + ((ks ^ (c & 7)) * 8)] = v;
  }
  float b1v = b1[col0 + rsel];
  __syncthreads();   // weights visible to all waves; after this, waves are autonomous

  const int rbase = rowstart + ksl * 4;
  const size_t hrow = (size_t)(rowstart + rsel) * HIDN;
  const unsigned* fptr = flags + 4 * lane;

  f16x8 hf[16];   // h0(p-1) after MAIN(p); h0(p-2) during SHADOW(p)
  f32x4 part1;

  for (int p = 0; p <= S_LEN + 1; ++p) {
    const bool doH0 = (p <= S_LEN - 1);
    const bool doH1 = (p >= 2);

    // ---- SHADOW ----
    if (doH1) {
      f32x4 t = {b1v, b1v, b1v, b1v};
#pragma unroll
      for (int kt = 0; kt < 16; ++kt) {
        int ks = kt * 4 + ksl;
        f16x8 b = *(const f16x8*)&wlds[1][rsel * 512 + ((ks ^ (rsel & 7)) * 8)];
        t = __builtin_amdgcn_mfma_f32_16x16x32_f16(hf[kt], b, t, 0, 0, 0);
      }
      part1 = t;
    }
    float pa0, pa1, pa2, pa3;
    if (doH0) {
      const int tbase = p * B_SZ + rbase;
      pa0 = (float)P0h[(size_t)tok[tbase + 0] * HIDN + col0 + rsel];
      pa1 = (float)P0h[(size_t)tok[tbase + 1] * HIDN + col0 + rsel];
      pa2 = (float)P0h[(size_t)tok[tbase + 2] * HIDN + col0 + rsel];
      pa3 = (float)P0h[(size_t)tok[tbase + 3] * HIDN + col0 + rsel];
      // pin: force gather completion here so compiler waitcnts stay out of MAIN
      asm volatile("" : "+v"(pa0), "+v"(pa1), "+v"(pa2), "+v"(pa3));
    }

    // ---- WAIT: all 256 wave-flags >= p ----
    if (p >= 1) {
      const unsigned tgt = (unsigned)p;
      for (;;) {
        u32x4 f;
        asm volatile("global_load_dwordx4 %0, %1, off sc1\n\ts_waitcnt vmcnt(0)"
                     : "=v"(f) : "v"(fptr) : "memory");
        int ok = (f[0] >= tgt) & (f[1] >= tgt) & (f[2] >= tgt) & (f[3] >= tgt);
        if (__all(ok)) break;
      }
    }

    // ---- MAIN: issue device-scope loads (hf first: critical path) ----
    if (p <= S_LEN) {
      const f16* src = h0ring + (size_t)((p - 1) & 3) * B_SZ * HIDN;
#pragma unroll
      for (int kt = 0; kt < 16; ++kt)
        hf[kt] = ld16_dev(src + hrow + kt * 32 + ksl * 8);
    }
    f16x8 h1f[16];
    if (doH1) {
      const f16* h1src = (p == 2) ? h1init : H1 + (size_t)(p - 3) * B_SZ * HIDN;
#pragma unroll
      for (int kt = 0; kt < 16; ++kt)
        h1f[kt] = ld16_dev(h1src + hrow + kt * 32 + ksl * 8);
    }

    if (doH0) {
      if (doH1) { VMCNT(16); } else { VMCNT(0); }   // hf ready; h1f may fly
      f32x4 acc0 = {pa0, pa1, pa2, pa3};
#pragma unroll
      for (int kt = 0; kt < 16; ++kt) {
        int ks = kt * 4 + ksl;
        f16x8 b = *(const f16x8*)&wlds[0][rsel * 512 + ((ks ^ (rsel & 7)) * 8)];
        acc0 = __builtin_amdgcn_mfma_f32_16x16x32_f16(hf[kt], b, acc0, 0, 0, 0);
      }
      f16* dst = h0ring + (size_t)(p & 3) * B_SZ * HIDN;
#pragma unroll
      for (int j = 0; j < 4; ++j) {
        float v = fast_tanh(acc0[j]);
        int r = rbase + j;
        cstore2(&dst[(size_t)r * HIDN + col0 + rsel], v);
        if (p == S_LEN - 1) outHid[(size_t)r * HIDN + col0 + rsel] = v;
      }
    }
    if (doH1) {
      if (doH0) { VMCNT(8); } else { VMCNT(0); }    // h1f (oldest 16) complete
      f32x4 acc1 = part1;
#pragma unroll
      for (int kt = 0; kt < 16; ++kt) {
        int ks = kt * 4 + ksl;
        f16x8 b = *(const f16x8*)&wlds[2][rsel * 512 + ((ks ^ (rsel & 7)) * 8)];
        acc1 = __builtin_amdgcn_mfma_f32_16x16x32_f16(h1f[kt], b, acc1, 0, 0, 0);
      }
      f16* h1dst = H1 + (size_t)(p - 2) * B_SZ * HIDN;
#pragma unroll
      for (int j = 0; j < 4; ++j) {
        float v = fast_tanh(acc1[j]);
        int r = rbase + j;
        cstore2(&h1dst[(size_t)r * HIDN + col0 + rsel], v);
        if (p == S_LEN + 1) outHid[(size_t)(B_SZ * HIDN) + (size_t)r * HIDN + col0 + rsel] = v;
      }
    }

    // ---- ARRIVE: per-wave drain + own-flag store ----
    if (p <= S_LEN) {
      VMCNT(0);
      if (lane == 0) stflag_dev((unsigned*)flags + fidx, (unsigned)(p + 1));
    }
  }
}

extern "C" void kernel_launch(void* const* d_in, const int* in_sizes, int n_in,
                              void* d_out, int out_size, void* d_ws, size_t ws_size,
                              hipStream_t stream) {
  (void)in_sizes; (void)n_in; (void)out_size; (void)ws_size;
  const int*   tok    = (const int*)d_in[0];
  const float* hidden = (const float*)d_in[1];
  const float* emb    = (const float*)d_in[2];
  const float* W0     = (const float*)d_in[3];
  const float* b0     = (const float*)d_in[4];
  const float* W1     = (const float*)d_in[5];
  const float* b1     = (const float*)d_in[6];
  const float* Wout   = (const float*)d_in[7];
  const float* bout   = (const float*)d_in[8];

  char* ws = (char*)d_ws;
  size_t off = 0;
  f16* embf16  = (f16*)(ws + off); off += (size_t)VPAD * 512 * 2;
  f16* woutf16 = (f16*)(ws + off); off += (size_t)VPAD * 512 * 2;
  f16* w0xf16  = (f16*)(ws + off); off += (size_t)512 * 512 * 2;
  f16* P0h     = (f16*)(ws + off); off += (size_t)VOC * 512 * 2;
  f16* H1      = (f16*)(ws + off); off += (size_t)S_LEN * B_SZ * 512 * 2;
  f16* h0ring  = (f16*)(ws + off); off += (size_t)4 * B_SZ * 512 * 2;
  f16* h1init  = (f16*)(ws + off); off += (size_t)B_SZ * 512 * 2;
  unsigned* flags = (unsigned*)(ws + off); off += NFLAG * 4;

  float* outHid = (float*)d_out + (size_t)S_LEN * B_SZ * VOC;

  hipMemsetAsync(flags, 0, NFLAG * 4, stream);   // reset flags each launch

  int tot = VPAD * 512;
  convert_pad<<<(tot + 255) / 256, 256, 0, stream>>>(emb,  embf16,  VOC, 512, tot);
  convert_pad<<<(tot + 255) / 256, 256, 0, stream>>>(Wout, woutf16, VOC, 512, tot);
  tot = 512 * 512;
  convert_pad<<<(tot + 255) / 256, 256, 0, stream>>>(W0, w0xf16, 512, 1024, tot);
  tot = B_SZ * 512;
  convert_pad<<<(tot + 255) / 256, 256, 0, stream>>>(hidden, h0ring + (size_t)3 * B_SZ * 512, B_SZ, 512, tot);
  convert_pad<<<(tot + 255) / 256, 256, 0, stream>>>(hidden + (size_t)B_SZ * 512, h1init, B_SZ, 512, tot);

  // P0 = emb @ W0x^T + b0  (f16 out, [10000][512])
  gemm_k512<f16><<<dim3(4, VPAD / 128), 256, 0, stream>>>(
      embf16, w0xf16, P0h, b0, VOC, 512, 512);

  // recurrence (cooperative for co-residency; wave-autonomous flag sync inside)
  {
    void* args[] = {(void*)&tok, (void*)&W0, (void*)&W1, (void*)&b1, (void*)&P0h,
                    (void*)&h0ring, (void*)&h1init, (void*)&H1, (void*)&outHid, (void*)&flags};
    hipLaunchCooperativeKernel((const void*)rnn_recur, dim3(NBLK), dim3(256), args, 0, stream);
  }

  // logits = H1 @ Wout^T + bout  -> d_out [16384][10000] fp32
  gemm_k512<float><<<dim3(79, 128), 256, 0, stream>>>(
      H1, woutf16, (float*)d_out, bout, S_LEN * B_SZ, VOC, VOC);
}